// Round 5
// baseline (51.468 us; speedup 1.0000x reference)
//
#include <hip/hip_runtime.h>

#define EPS 1e-8f

// Shapes fixed per reference: x [B=8, N=8192, D=512] fp32, scalar fp32 out.
#define B_DIM 8
#define N_DIM 8192
#define D_DIM 512
#define CHUNKS 256   // K1 grid = B*CHUNKS = 2048 blocks (8/CU -> 32 waves/CU)

typedef float fx4 __attribute__((ext_vector_type(4)));

// K1: 256 threads (4 waves). Each wave processes rowsPerWave consecutive rows,
// 2 rows per iteration + 2-row-ahead prefetch; lane l owns d-slice [8l, 8l+8).
// Block writes one 512-float partial sum vector (sum of normalized rows).
__global__ __launch_bounds__(256) void k1_partial(const float* __restrict__ x,
                                                  float* __restrict__ partial) {
    const int blk   = blockIdx.x;
    const int b     = blk >> 8;            // / CHUNKS
    const int chunk = blk & (CHUNKS - 1);
    const int wave  = threadIdx.x >> 6;    // 0..3
    const int lane  = threadIdx.x & 63;
    const int rowsPerChunk = N_DIM / CHUNKS;      // 32
    const int rowsPerWave  = rowsPerChunk >> 2;   // 8

    const long long rowStart = (long long)b * N_DIM
                             + (long long)chunk * rowsPerChunk
                             + (long long)wave * rowsPerWave;

    float acc[8];
    #pragma unroll
    for (int k = 0; k < 8; ++k) acc[k] = 0.0f;

    const float* base = x + rowStart * D_DIM + lane * 8;

    // prologue: rows 0,1 in flight
    fx4 a0 = __builtin_nontemporal_load((const fx4*)(base));
    fx4 a1 = __builtin_nontemporal_load((const fx4*)(base + 4));
    fx4 b0 = __builtin_nontemporal_load((const fx4*)(base + D_DIM));
    fx4 b1 = __builtin_nontemporal_load((const fx4*)(base + D_DIM + 4));

    for (int r = 0; r < rowsPerWave; r += 2) {
        // prefetch rows r+2, r+3 before consuming rows r, r+1
        fx4 c0, c1, e0, e1;
        const bool more = (r + 2) < rowsPerWave;
        if (more) {
            const float* nb = base + 2 * D_DIM;
            c0 = __builtin_nontemporal_load((const fx4*)(nb));
            c1 = __builtin_nontemporal_load((const fx4*)(nb + 4));
            e0 = __builtin_nontemporal_load((const fx4*)(nb + D_DIM));
            e1 = __builtin_nontemporal_load((const fx4*)(nb + D_DIM + 4));
        }
        base += 2 * D_DIM;

        float ssA = a0.x*a0.x + a0.y*a0.y + a0.z*a0.z + a0.w*a0.w
                  + a1.x*a1.x + a1.y*a1.y + a1.z*a1.z + a1.w*a1.w;
        float ssB = b0.x*b0.x + b0.y*b0.y + b0.z*b0.z + b0.w*b0.w
                  + b1.x*b1.x + b1.y*b1.y + b1.z*b1.z + b1.w*b1.w;

        // two interleaved 64-lane butterflies (independent chains)
        #pragma unroll
        for (int off = 1; off < 64; off <<= 1) {
            ssA += __shfl_xor(ssA, off);
            ssB += __shfl_xor(ssB, off);
        }

        const float invA = 1.0f / fmaxf(sqrtf(ssA), EPS);
        const float invB = 1.0f / fmaxf(sqrtf(ssB), EPS);

        acc[0] += a0.x * invA + b0.x * invB;
        acc[1] += a0.y * invA + b0.y * invB;
        acc[2] += a0.z * invA + b0.z * invB;
        acc[3] += a0.w * invA + b0.w * invB;
        acc[4] += a1.x * invA + b1.x * invB;
        acc[5] += a1.y * invA + b1.y * invB;
        acc[6] += a1.z * invA + b1.z * invB;
        acc[7] += a1.w * invA + b1.w * invB;

        if (more) { a0 = c0; a1 = c1; b0 = e0; b1 = e1; }
    }

    // combine the 4 waves' partials deterministically via LDS
    __shared__ float lds[4][D_DIM];
    float* dst = &lds[wave][lane * 8];
    #pragma unroll
    for (int k = 0; k < 8; ++k) dst[k] = acc[k];
    __syncthreads();

    for (int d = threadIdx.x; d < D_DIM; d += 256) {
        float s = lds[0][d] + lds[1][d] + lds[2][d] + lds[3][d];
        partial[(long long)blk * D_DIM + d] = s;
    }
}

// K2: 64 blocks = 8 batches x 8 d-groups (64 d's each), 256 threads.
// Wave q sums chunks c === q (mod 4) for its 64 d's; LDS-combine the 4 waves,
// square, 64-lane reduce -> one partial ssq per block.
__global__ __launch_bounds__(256) void k2_batch(const float* __restrict__ partial,
                                                float* __restrict__ ssqPartial) {
    const int b  = blockIdx.x >> 3;
    const int g  = blockIdx.x & 7;
    const int dl = threadIdx.x & 63;
    const int q  = threadIdx.x >> 6;
    const int d  = g * 64 + dl;

    float s = 0.0f;
    const float* p = partial + (long long)b * CHUNKS * D_DIM + d;
    for (int c = q; c < CHUNKS; c += 4) s += p[(long long)c * D_DIM];

    __shared__ float lds[4][64];
    lds[q][dl] = s;
    __syncthreads();

    if (q == 0) {
        const float tot = lds[0][dl] + lds[1][dl] + lds[2][dl] + lds[3][dl];
        float v = tot * tot;
        #pragma unroll
        for (int off = 1; off < 64; off <<= 1) v += __shfl_xor(v, off);
        if (dl == 0) ssqPartial[blockIdx.x] = v;
    }
}

// K3: 64 partial ssq values -> scalar.
__global__ void k3_final(const float* __restrict__ ssqPartial,
                         float* __restrict__ out) {
    float v = ssqPartial[threadIdx.x & 63];
    #pragma unroll
    for (int off = 1; off < 64; off <<= 1) v += __shfl_xor(v, off);
    if (threadIdx.x == 0)
        out[0] = v / ((float)N_DIM * (float)N_DIM * (float)B_DIM);
}

extern "C" void kernel_launch(void* const* d_in, const int* in_sizes, int n_in,
                              void* d_out, int out_size, void* d_ws, size_t ws_size,
                              hipStream_t stream) {
    const float* x = (const float*)d_in[0];
    float* out = (float*)d_out;

    float* partial    = (float*)d_ws;                               // B*CHUNKS*512 floats = 4 MB
    float* ssqPartial = partial + (size_t)B_DIM * CHUNKS * D_DIM;   // 64 floats

    k1_partial<<<dim3(B_DIM * CHUNKS), dim3(256), 0, stream>>>(x, partial);
    k2_batch<<<dim3(B_DIM * 8), dim3(256), 0, stream>>>(partial, ssqPartial);
    k3_final<<<dim3(1), dim3(64), 0, stream>>>(ssqPartial, out);
}

// Round 6
// 38.209 us; speedup vs baseline: 1.3470x; 1.3470x over previous
//
#include <hip/hip_runtime.h>

#define EPS 1e-8f

// Shapes fixed per reference: x [B=8, N=8192, D=512] fp32, scalar fp32 out.
#define B_DIM 8
#define N_DIM 8192
#define D_DIM 512
#define CHUNKS 128   // K1 grid = B*CHUNKS = 1024 blocks (4/CU, 16 waves/CU)

typedef float fx4 __attribute__((ext_vector_type(4)));

// K1: 256 threads (4 waves). Each wave processes 16 consecutive rows,
// 4 rows per iteration (8x dwordx4 in flight, 4 interleaved butterflies);
// lane l owns d-slice [8l, 8l+8). Block writes one 512-float partial vector.
__global__ __launch_bounds__(256) void k1_partial(const float* __restrict__ x,
                                                  float* __restrict__ partial) {
    const int blk   = blockIdx.x;
    const int b     = blk >> 7;            // / CHUNKS
    const int chunk = blk & (CHUNKS - 1);
    const int wave  = threadIdx.x >> 6;    // 0..3
    const int lane  = threadIdx.x & 63;
    const int rowsPerChunk = N_DIM / CHUNKS;      // 64
    const int rowsPerWave  = rowsPerChunk >> 2;   // 16

    const long long rowStart = (long long)b * N_DIM
                             + (long long)chunk * rowsPerChunk
                             + (long long)wave * rowsPerWave;

    float acc[8];
    #pragma unroll
    for (int k = 0; k < 8; ++k) acc[k] = 0.0f;

    const float* base = x + rowStart * D_DIM + lane * 8;

    for (int r = 0; r < rowsPerWave; r += 4) {
        fx4 v[4][2];
        #pragma unroll
        for (int i = 0; i < 4; ++i) {
            v[i][0] = *(const fx4*)(base + i * D_DIM);
            v[i][1] = *(const fx4*)(base + i * D_DIM + 4);
        }
        base += 4 * D_DIM;

        float ss[4];
        #pragma unroll
        for (int i = 0; i < 4; ++i) {
            ss[i] = v[i][0].x*v[i][0].x + v[i][0].y*v[i][0].y
                  + v[i][0].z*v[i][0].z + v[i][0].w*v[i][0].w
                  + v[i][1].x*v[i][1].x + v[i][1].y*v[i][1].y
                  + v[i][1].z*v[i][1].z + v[i][1].w*v[i][1].w;
        }

        // four interleaved 64-lane butterflies (independent chains)
        #pragma unroll
        for (int off = 1; off < 64; off <<= 1) {
            #pragma unroll
            for (int i = 0; i < 4; ++i) ss[i] += __shfl_xor(ss[i], off);
        }

        #pragma unroll
        for (int i = 0; i < 4; ++i) {
            const float inv = 1.0f / fmaxf(sqrtf(ss[i]), EPS);
            acc[0] += v[i][0].x * inv;
            acc[1] += v[i][0].y * inv;
            acc[2] += v[i][0].z * inv;
            acc[3] += v[i][0].w * inv;
            acc[4] += v[i][1].x * inv;
            acc[5] += v[i][1].y * inv;
            acc[6] += v[i][1].z * inv;
            acc[7] += v[i][1].w * inv;
        }
    }

    // combine the 4 waves' partials deterministically via LDS
    __shared__ float lds[4][D_DIM];
    float* dst = &lds[wave][lane * 8];
    #pragma unroll
    for (int k = 0; k < 8; ++k) dst[k] = acc[k];
    __syncthreads();

    for (int d = threadIdx.x; d < D_DIM; d += 256) {
        float s = lds[0][d] + lds[1][d] + lds[2][d] + lds[3][d];
        partial[(long long)blk * D_DIM + d] = s;
    }
}

// K2: 64 blocks = 8 batches x 8 d-groups (64 d's each), 256 threads.
// Wave q sums chunks c === q (mod 4) for its 64 d's; LDS-combine the 4 waves,
// square, 64-lane reduce -> one partial ssq per block.
__global__ __launch_bounds__(256) void k2_batch(const float* __restrict__ partial,
                                                float* __restrict__ ssqPartial) {
    const int b  = blockIdx.x >> 3;
    const int g  = blockIdx.x & 7;
    const int dl = threadIdx.x & 63;
    const int q  = threadIdx.x >> 6;
    const int d  = g * 64 + dl;

    float s = 0.0f;
    const float* p = partial + (long long)b * CHUNKS * D_DIM + d;
    for (int c = q; c < CHUNKS; c += 4) s += p[(long long)c * D_DIM];

    __shared__ float lds[4][64];
    lds[q][dl] = s;
    __syncthreads();

    if (q == 0) {
        const float tot = lds[0][dl] + lds[1][dl] + lds[2][dl] + lds[3][dl];
        float v = tot * tot;
        #pragma unroll
        for (int off = 1; off < 64; off <<= 1) v += __shfl_xor(v, off);
        if (dl == 0) ssqPartial[blockIdx.x] = v;
    }
}

// K3: 64 partial ssq values -> scalar.
__global__ void k3_final(const float* __restrict__ ssqPartial,
                         float* __restrict__ out) {
    float v = ssqPartial[threadIdx.x & 63];
    #pragma unroll
    for (int off = 1; off < 64; off <<= 1) v += __shfl_xor(v, off);
    if (threadIdx.x == 0)
        out[0] = v / ((float)N_DIM * (float)N_DIM * (float)B_DIM);
}

extern "C" void kernel_launch(void* const* d_in, const int* in_sizes, int n_in,
                              void* d_out, int out_size, void* d_ws, size_t ws_size,
                              hipStream_t stream) {
    const float* x = (const float*)d_in[0];
    float* out = (float*)d_out;

    float* partial    = (float*)d_ws;                               // B*CHUNKS*512 floats = 2 MB
    float* ssqPartial = partial + (size_t)B_DIM * CHUNKS * D_DIM;   // 64 floats

    k1_partial<<<dim3(B_DIM * CHUNKS), dim3(256), 0, stream>>>(x, partial);
    k2_batch<<<dim3(B_DIM * 8), dim3(256), 0, stream>>>(partial, ssqPartial);
    k3_final<<<dim3(1), dim3(64), 0, stream>>>(ssqPartial, out);
}

// Round 7
// 38.114 us; speedup vs baseline: 1.3504x; 1.0025x over previous
//
#include <hip/hip_runtime.h>

#define EPS 1e-8f

// Shapes fixed per reference: x [B=8, N=8192, D=512] fp32, scalar fp32 out.
#define B_DIM 8
#define N_DIM 8192
#define D_DIM 512
#define CHUNKS 128   // K1 grid = B*CHUNKS = 1024 blocks (4/CU, 16 waves/CU)
#define FIX_SCALE 1099511627776.0   // 2^40 fixed-point scale for deterministic sum

typedef float fx4 __attribute__((ext_vector_type(4)));

// K1: 256 threads (4 waves). Each wave processes 16 consecutive rows,
// 4 rows per iteration; lane l owns d-slice [8l, 8l+8).
// Block writes one 512-float partial vector. Block 0 also zeroes the
// K2 accumulator/ticket (safe: K1 fully precedes K2 in stream order).
__global__ __launch_bounds__(256) void k1_partial(const float* __restrict__ x,
                                                  float* __restrict__ partial,
                                                  unsigned long long* __restrict__ acc,
                                                  unsigned int* __restrict__ ticket) {
    if (blockIdx.x == 0 && threadIdx.x == 0) { *acc = 0ULL; *ticket = 0U; }

    const int blk   = blockIdx.x;
    const int b     = blk >> 7;            // / CHUNKS
    const int chunk = blk & (CHUNKS - 1);
    const int wave  = threadIdx.x >> 6;    // 0..3
    const int lane  = threadIdx.x & 63;
    const int rowsPerChunk = N_DIM / CHUNKS;      // 64
    const int rowsPerWave  = rowsPerChunk >> 2;   // 16

    const long long rowStart = (long long)b * N_DIM
                             + (long long)chunk * rowsPerChunk
                             + (long long)wave * rowsPerWave;

    float accv[8];
    #pragma unroll
    for (int k = 0; k < 8; ++k) accv[k] = 0.0f;

    const float* base = x + rowStart * D_DIM + lane * 8;

    for (int r = 0; r < rowsPerWave; r += 4) {
        fx4 v[4][2];
        #pragma unroll
        for (int i = 0; i < 4; ++i) {
            v[i][0] = *(const fx4*)(base + i * D_DIM);
            v[i][1] = *(const fx4*)(base + i * D_DIM + 4);
        }
        base += 4 * D_DIM;

        float ss[4];
        #pragma unroll
        for (int i = 0; i < 4; ++i) {
            ss[i] = v[i][0].x*v[i][0].x + v[i][0].y*v[i][0].y
                  + v[i][0].z*v[i][0].z + v[i][0].w*v[i][0].w
                  + v[i][1].x*v[i][1].x + v[i][1].y*v[i][1].y
                  + v[i][1].z*v[i][1].z + v[i][1].w*v[i][1].w;
        }

        // four interleaved 64-lane butterflies (independent chains)
        #pragma unroll
        for (int off = 1; off < 64; off <<= 1) {
            #pragma unroll
            for (int i = 0; i < 4; ++i) ss[i] += __shfl_xor(ss[i], off);
        }

        #pragma unroll
        for (int i = 0; i < 4; ++i) {
            const float inv = 1.0f / fmaxf(sqrtf(ss[i]), EPS);
            accv[0] += v[i][0].x * inv;
            accv[1] += v[i][0].y * inv;
            accv[2] += v[i][0].z * inv;
            accv[3] += v[i][0].w * inv;
            accv[4] += v[i][1].x * inv;
            accv[5] += v[i][1].y * inv;
            accv[6] += v[i][1].z * inv;
            accv[7] += v[i][1].w * inv;
        }
    }

    // combine the 4 waves' partials deterministically via LDS
    __shared__ float lds[4][D_DIM];
    float* dst = &lds[wave][lane * 8];
    #pragma unroll
    for (int k = 0; k < 8; ++k) dst[k] = accv[k];
    __syncthreads();

    for (int d = threadIdx.x; d < D_DIM; d += 256) {
        float s = lds[0][d] + lds[1][d] + lds[2][d] + lds[3][d];
        partial[(long long)blk * D_DIM + d] = s;
    }
}

// K2: 64 blocks = 8 batches x 8 d-groups (64 d's each), 256 threads.
// Wave q sums chunks c === q (mod 4) for its 64 d's; LDS-combine the 4 waves,
// square, 64-lane reduce -> block ssq. Each block adds its ssq (fixed-point
// u64, order-independent = deterministic) to *acc; the last block (ticket 63)
// writes the final scalar.
__global__ __launch_bounds__(256) void k2_batch(const float* __restrict__ partial,
                                                unsigned long long* __restrict__ acc,
                                                unsigned int* __restrict__ ticket,
                                                float* __restrict__ out) {
    const int b  = blockIdx.x >> 3;
    const int g  = blockIdx.x & 7;
    const int dl = threadIdx.x & 63;
    const int q  = threadIdx.x >> 6;
    const int d  = g * 64 + dl;

    float s = 0.0f;
    const float* p = partial + (long long)b * CHUNKS * D_DIM + d;
    for (int c = q; c < CHUNKS; c += 4) s += p[(long long)c * D_DIM];

    __shared__ float lds[4][64];
    lds[q][dl] = s;
    __syncthreads();

    if (q == 0) {
        const float tot = lds[0][dl] + lds[1][dl] + lds[2][dl] + lds[3][dl];
        float v = tot * tot;
        #pragma unroll
        for (int off = 1; off < 64; off <<= 1) v += __shfl_xor(v, off);

        if (dl == 0) {
            const long long q64 = (long long)((double)v * FIX_SCALE);
            atomicAdd(acc, (unsigned long long)q64);
            __threadfence();
            const unsigned int t = atomicAdd(ticket, 1U);
            if (t == (B_DIM * 8 - 1)) {
                const unsigned long long totu = atomicAdd(acc, 0ULL);
                const double tot_d = (double)(long long)totu / FIX_SCALE;
                out[0] = (float)(tot_d / ((double)N_DIM * (double)N_DIM * (double)B_DIM));
            }
        }
    }
}

extern "C" void kernel_launch(void* const* d_in, const int* in_sizes, int n_in,
                              void* d_out, int out_size, void* d_ws, size_t ws_size,
                              hipStream_t stream) {
    const float* x = (const float*)d_in[0];
    float* out = (float*)d_out;

    float* partial = (float*)d_ws;                                  // B*CHUNKS*512 floats = 2 MB
    unsigned long long* acc = (unsigned long long*)((char*)d_ws +
                              (size_t)B_DIM * CHUNKS * D_DIM * sizeof(float));
    unsigned int* ticket = (unsigned int*)(acc + 1);

    k1_partial<<<dim3(B_DIM * CHUNKS), dim3(256), 0, stream>>>(x, partial, acc, ticket);
    k2_batch<<<dim3(B_DIM * 8), dim3(256), 0, stream>>>(partial, acc, ticket, out);
}